// Round 5
// baseline (2788.854 us; speedup 1.0000x reference)
//
#include <hip/hip_runtime.h>
#include <hip/hip_cooperative_groups.h>

namespace cg = cooperative_groups;

#define M_TOTAL 65536   // B*T rows
#define DDIM    128     // latent dim (GEMM K)
#define KCODES  1024    // codebook size (GEMM N)
#define NQ      8       // RVQ stages
#define RROWS   64      // rows per block -> 1024 blocks = exactly 4/CU co-resident
#define NC      64      // codes per Es chunk
#define NCHUNKS (KCODES / NC)          // 16
#define CHUNK_B (NC * DDIM * 2)        // 16384 B per f16 chunk
#define TAU     0.15f   // margin threshold in REF dist units (validated; screen dist = ref/2)
#define FB      8       // fixup rows per batched codebook scan
#define FIXGRID 256     // fixup sweep blocks (round-0 validated geometry)

typedef _Float16 half8 __attribute__((ext_vector_type(8)));
typedef float    f32x4 __attribute__((ext_vector_type(4)));

// direct global->LDS copy, 16 B per lane; LDS dest is wave-uniform base + lane*16
__device__ __forceinline__ void gld_lds16(const void* g, void* l) {
  __builtin_amdgcn_global_load_lds(
      (const __attribute__((address_space(1))) unsigned int*)g,
      (__attribute__((address_space(3))) unsigned int*)l, 16, 0, 0);
}

// ---------------- ||e||^2 (verified round-1 semantics) + nfp zeroing ----------------
__global__ __launch_bounds__(256) void enorm_kernel(const float* __restrict__ embed,
                                                    float* __restrict__ enorm,
                                                    int* __restrict__ nfp) {
  if (blockIdx.x == 0 && threadIdx.x < NQ) nfp[threadIdx.x] = 0;
  int c = blockIdx.x * 4 + (threadIdx.x >> 6);
  int lane = threadIdx.x & 63;
  const float* e = embed + (size_t)c * DDIM;
  float v0 = e[lane];
  float v1 = e[lane + 64];
  float s = fmaf(v0, v0, v1 * v1);
  #pragma unroll
  for (int off = 32; off > 0; off >>= 1) s += __shfl_down(s, off);
  if (lane == 0) enorm[c] = s;
}

// ---------------- embed -> f16 plane, PRE-SWIZZLED for linear global_load_lds ----
// 16B block j of code c stored at block position j ^ (c&7): after a linear
// global->LDS copy the screen's 16-lane row-strided ds_read_b128 spreads over
// all bank stripes.
__global__ __launch_bounds__(256) void esplit16_kernel(const float* __restrict__ embed,
                                                       _Float16* __restrict__ Ef16) {
  unsigned u = blockIdx.x * 256 + threadIdx.x;          // half8 index: ((s*1024+c)*16+j)
  size_t src = (size_t)u * 8;
  float4 v0 = *(const float4*)(embed + src);
  float4 v1 = *(const float4*)(embed + src + 4);
  half8 h;
  h[0] = (_Float16)v0.x; h[1] = (_Float16)v0.y; h[2] = (_Float16)v0.z; h[3] = (_Float16)v0.w;
  h[4] = (_Float16)v1.x; h[5] = (_Float16)v1.y; h[6] = (_Float16)v1.z; h[7] = (_Float16)v1.w;
  unsigned row = u >> 4;                                // s*1024 + c
  unsigned j   = u & 15;
  size_t dst = (size_t)row * 128 + 8 * (j ^ (row & 7)); // (row&7) == (c&7)
  *(half8*)(Ef16 + dst) = h;
}

// ---------------- shared-memory layouts (union: phases never overlap) ----------------
struct ScreenSmem {
  char  EsU[2 * CHUNK_B];            // 32768 B Es double-buffer
  float redv1[RROWS * 2];
  float redv2[RROWS * 2];
  int   redi1[RROWS * 2];
  int   bcode[RROWS];
};                                    // 34560 B
struct FixSmem {
  float rowbuf[FB][DDIM];            // 4096 B
  float wv_v[4];
  int   wv_i[4];
  int   rowid[FB];
  int   bestc[FB];
};                                    // 4192 B
union CoopSmem { ScreenSmem s; FixSmem f; };

// ---------------- screen stage (round-2-validated body, global flag list) ----------
// dist = dot - ||e||^2/2 (= ref_dist/2, folded into MFMA acc init); top-2 via
// med3; codes ascend -> strict > keeps first occurrence; margin <= TAU/2 flags
// the row into the GLOBAL list for the central fixup sweep.
__device__ __forceinline__ void screen_stage(
    ScreenSmem& S,
    const float* rin, float* rout,        // no __restrict__: in-place for st>=1
    const _Float16* __restrict__ EfS,
    const float* __restrict__ embS,
    const float* __restrict__ enS,
    int* __restrict__ codesS,
    int* __restrict__ flistS, int* __restrict__ nfpS,
    int write_resid)
{
  const int tid = threadIdx.x;
  const int wv = tid >> 6;
  const int lane = tid & 63;
  const int l15 = lane & 15;
  const int q = lane >> 4;
  const int rw = wv & 1;          // row-half of the 2x2 wave grid
  const int cw = wv >> 1;         // code-half
  const int row_base = blockIdx.x * RROWS;
  const int rx = cw * 32 + l15;   // B-frag row within chunk (ct=0); ct=1 adds 16
  const int xr = rx & 7;          // Es bank swizzle key
  char* const esB = S.EsU;

  // ---- A-frags from global rin (L1-absorbed cw duplication) ----
  half8 af[2][4];
  #pragma unroll
  for (int rt = 0; rt < 2; ++rt) {
    const float* pa = rin + (size_t)(row_base + rw * 32 + rt * 16 + l15) * DDIM;
    #pragma unroll
    for (int kc = 0; kc < 4; ++kc) {
      float4 x0 = *(const float4*)(pa + kc * 32 + q * 8);
      float4 x1 = *(const float4*)(pa + kc * 32 + q * 8 + 4);
      half8 h;
      h[0] = (_Float16)x0.x; h[1] = (_Float16)x0.y; h[2] = (_Float16)x0.z; h[3] = (_Float16)x0.w;
      h[4] = (_Float16)x1.x; h[5] = (_Float16)x1.y; h[6] = (_Float16)x1.z; h[7] = (_Float16)x1.w;
      af[rt][kc] = h;
    }
  }

  // ---- prologue: stage chunk 0 (linear gld_lds == pre-swizzled layout) ----
  {
    const char* g = (const char*)EfS;
    #pragma unroll
    for (int it = 0; it < 4; ++it) {
      const int off = it * 4096 + wv * 1024;
      gld_lds16(g + off + lane * 16, esB + off);
    }
  }
  float enr0 = enS[cw * 32 + l15];
  float enr1 = enS[cw * 32 + 16 + l15];
  __syncthreads();                // vmcnt drained before barrier; chunk 0 ready

  float v1[8], v2[8];
  int i1[8];
  #pragma unroll
  for (int sI = 0; sI < 8; ++sI) { v1[sI] = -3.0e38f; v2[sI] = -3.0e38f; i1[sI] = 0x7fffffff; }

  for (int cc = 0; cc < NCHUNKS; ++cc) {
    const int cur = cc & 1;
    if (cc + 1 < NCHUNKS) {       // prefetch next chunk (full-chunk latency window)
      const char* g = (const char*)EfS + (size_t)(cc + 1) * CHUNK_B;
      char* l = esB + (cur ^ 1) * CHUNK_B;
      #pragma unroll
      for (int it = 0; it < 4; ++it) {
        const int off = it * 4096 + wv * 1024;
        gld_lds16(g + off + lane * 16, l + off);
      }
    }
    float nh0 = -0.5f * enr0;     // folded: d = dot - ||e||^2/2 = ref_dist/2
    float nh1 = -0.5f * enr1;
    if (cc + 1 < NCHUNKS) {       // pipeline next chunk's enorm
      enr0 = enS[(cc + 1) * NC + cw * 32 + l15];
      enr1 = enS[(cc + 1) * NC + cw * 32 + 16 + l15];
    }
    f32x4 acc[2][2];
    #pragma unroll
    for (int rt = 0; rt < 2; ++rt) {
      acc[rt][0] = (f32x4){nh0, nh0, nh0, nh0};
      acc[rt][1] = (f32x4){nh1, nh1, nh1, nh1};
    }

    const char* eb = esB + cur * CHUNK_B;
    #pragma unroll
    for (int kc = 0; kc < 4; ++kc) {
      const int jswz = 16 * ((kc * 4 + q) ^ xr);
      half8 bf0 = *(const half8*)(eb + rx * 256 + jswz);
      half8 bf1 = *(const half8*)(eb + (rx + 16) * 256 + jswz);
      #pragma unroll
      for (int rt = 0; rt < 2; ++rt) {
        acc[rt][0] = __builtin_amdgcn_mfma_f32_16x16x32_f16(af[rt][kc], bf0, acc[rt][0], 0, 0, 0);
        acc[rt][1] = __builtin_amdgcn_mfma_f32_16x16x32_f16(af[rt][kc], bf1, acc[rt][1], 0, 0, 0);
      }
    }

    // top-2 epilogue (med3 second-max)
    #pragma unroll
    for (int ct = 0; ct < 2; ++ct) {
      const int cgi = cc * NC + cw * 32 + ct * 16 + l15;
      #pragma unroll
      for (int rt = 0; rt < 2; ++rt)
        #pragma unroll
        for (int reg = 0; reg < 4; ++reg) {
          float d = acc[rt][ct][reg];
          int s = rt * 4 + reg;
          v2[s] = __builtin_amdgcn_fmed3f(d, v1[s], v2[s]);
          if (d > v1[s]) i1[s] = cgi;
          v1[s] = fmaxf(v1[s], d);
        }
    }
    __syncthreads();              // next buffer staged + this buffer reusable
  }

  // ---- merge top-2 across the 16 l15-lanes sharing each row (disjoint codes) ----
  #pragma unroll
  for (int sI = 0; sI < 8; ++sI) {
    #pragma unroll
    for (int off = 1; off < 16; off <<= 1) {
      float ov1 = __shfl_xor(v1[sI], off);
      int   oi1 = __shfl_xor(i1[sI], off);
      float ov2 = __shfl_xor(v2[sI], off);
      if (ov1 > v1[sI] || (ov1 == v1[sI] && oi1 < i1[sI])) {
        float nv2 = fmaxf(v1[sI], ov2);
        v1[sI] = ov1; i1[sI] = oi1; v2[sI] = nv2;
      } else {
        v2[sI] = fmaxf(v2[sI], ov1);
      }
    }
  }
  if (l15 == 0) {
    #pragma unroll
    for (int sI = 0; sI < 8; ++sI) {
      int row = rw * 32 + (sI >> 2) * 16 + q * 4 + (sI & 3);
      S.redv1[row * 2 + cw] = v1[sI];
      S.redi1[row * 2 + cw] = i1[sI];
      S.redv2[row * 2 + cw] = v2[sI];
    }
  }
  __syncthreads();

  // ---- final per-row merge, screen codes out, flag to GLOBAL list ----
  if (tid < RROWS) {
    float a1 = S.redv1[tid * 2], a2 = S.redv2[tid * 2];
    int ai = S.redi1[tid * 2];
    float b1v = S.redv1[tid * 2 + 1], b2v = S.redv2[tid * 2 + 1];
    int bi = S.redi1[tid * 2 + 1];
    float bv1, bv2; int bidx;
    if (b1v > a1 || (b1v == a1 && bi < ai)) {
      bv1 = b1v; bidx = bi; bv2 = fmaxf(a1, b2v);
    } else {
      bv1 = a1; bidx = ai; bv2 = fmaxf(b1v, a2);
    }
    S.bcode[tid] = bidx;
    codesS[row_base + tid] = bidx;
    if (bv1 - bv2 <= TAU * 0.5f) {         // screen dist scale is ref/2
      int pos = atomicAdd(nfpS, 1);
      flistS[pos] = row_base + tid;
    }
  }
  __syncthreads();

  // ---- exact f32 residual update with screen codes (fixup rewrites flagged rows) ----
  if (write_resid) {
    #pragma unroll
    for (int it = 0; it < 8; ++it) {
      int idx = it * 256 + tid;
      int r = idx >> 5, f4 = idx & 31;
      float4 e = *(const float4*)(embS + (size_t)S.bcode[r] * DDIM + f4 * 4);
      float4 a = *(const float4*)(rin + (size_t)(row_base + r) * DDIM + f4 * 4);
      float4 o;
      o.x = a.x - e.x; o.y = a.y - e.y; o.z = a.z - e.z; o.w = a.w - e.w;
      *(float4*)(rout + (size_t)(row_base + r) * DDIM + f4 * 4) = o;
    }
  }
}

// ---------------- central batched exact fixup (round-0-validated body) ----------------
__device__ __forceinline__ void fixup_stage(
    FixSmem& F,
    const float* __restrict__ x,
    const float* __restrict__ embed_all, const float* __restrict__ enorm_all,
    int* __restrict__ codes, float* __restrict__ resid,
    const int* __restrict__ flistS, const int* __restrict__ nfpS,
    int stage, int write_resid)
{
  const int tid = threadIdx.x;
  const int lane = tid & 63;
  const int wv = tid >> 6;
  const int n = *nfpS;
  const float* embedS = embed_all + (size_t)stage * KCODES * DDIM;
  const float* enormS = enorm_all + (size_t)stage * KCODES;

  for (int base = blockIdx.x * FB; base < n; base += FIXGRID * FB) {
    const int nb = min(FB, n - base);
    if (tid < nb) F.rowid[tid] = flistS[base + tid];
    __syncthreads();

    // reconstruct exact residual: v = x - sum_{s2<stage} embed[codes[s2]] (stage order)
    for (int j0 = 0; j0 < nb; j0 += 2) {
      int j = j0 + (tid >> 7);
      int d = tid & 127;
      if (j < nb) {
        int r = F.rowid[j];
        float v = x[(size_t)r * DDIM + d];
        for (int s2 = 0; s2 < stage; ++s2) {
          int pc = codes[(size_t)s2 * M_TOTAL + r];
          v -= embed_all[(size_t)(s2 * KCODES + pc) * DDIM + d];
        }
        F.rowbuf[j][d] = v;
      }
    }
    __syncthreads();

    // exact dots: thread t -> codes {4t..4t+3} x FB rows, sequential-k fmaf chains
    float acc[4][FB];
    #pragma unroll
    for (int jc = 0; jc < 4; ++jc)
      #pragma unroll
      for (int j = 0; j < FB; ++j) acc[jc][j] = 0.f;
    for (int k4 = 0; k4 < 32; ++k4) {
      float4 rb[FB];
      #pragma unroll
      for (int j = 0; j < FB; ++j) rb[j] = *(const float4*)(&F.rowbuf[j][k4 * 4]);
      #pragma unroll
      for (int jc = 0; jc < 4; ++jc) {
        float4 e4 = *(const float4*)(embedS + (size_t)(tid * 4 + jc) * DDIM + k4 * 4);
        #pragma unroll
        for (int j = 0; j < FB; ++j) {
          acc[jc][j] = fmaf(rb[j].x, e4.x, acc[jc][j]);
          acc[jc][j] = fmaf(rb[j].y, e4.y, acc[jc][j]);
          acc[jc][j] = fmaf(rb[j].z, e4.z, acc[jc][j]);
          acc[jc][j] = fmaf(rb[j].w, e4.w, acc[jc][j]);
        }
      }
    }

    for (int j = 0; j < nb; ++j) {
      float bv = -3.0e38f; int bi = 0x7fffffff;
      #pragma unroll
      for (int jc = 0; jc < 4; ++jc) {
        int c = tid * 4 + jc;
        float dd = 2.0f * acc[jc][j] - enormS[c];
        if (dd > bv) { bv = dd; bi = c; }      // jc ascending -> first occurrence
      }
      #pragma unroll
      for (int off = 32; off > 0; off >>= 1) {
        float o = __shfl_down(bv, off);
        int oi = __shfl_down(bi, off);
        if (o > bv || (o == bv && oi < bi)) { bv = o; bi = oi; }
      }
      if (lane == 0) { F.wv_v[wv] = bv; F.wv_i[wv] = bi; }
      __syncthreads();
      if (tid == 0) {
        float fbv = F.wv_v[0]; int fbi = F.wv_i[0];
        #pragma unroll
        for (int w = 1; w < 4; ++w) {
          float o = F.wv_v[w]; int oi = F.wv_i[w];
          if (o > fbv || (o == fbv && oi < fbi)) { fbv = o; fbi = oi; }
        }
        F.bestc[j] = fbi;
        codes[(size_t)stage * M_TOTAL + F.rowid[j]] = fbi;
      }
      __syncthreads();
    }

    // rewrite exact f32 residual for flagged rows
    if (write_resid) {
      for (int j0 = 0; j0 < nb; j0 += 2) {
        int j = j0 + (tid >> 7);
        int d = tid & 127;
        if (j < nb) {
          int r = F.rowid[j];
          resid[(size_t)r * DDIM + d] = F.rowbuf[j][d] - embedS[(size_t)F.bestc[j] * DDIM + d];
        }
      }
    }
    __syncthreads();
  }
}

// ---------------- cooperative fused driver: 16 grid syncs replace 16 launch gaps ----
__global__ __launch_bounds__(256, 4) void rvq_coop(
    const float* __restrict__ x, float* __restrict__ resid,
    const float* __restrict__ embed, const _Float16* __restrict__ Ef16,
    const float* __restrict__ enorm, int* __restrict__ codes,
    int* __restrict__ flist, int* __restrict__ nfp)
{
  __shared__ __attribute__((aligned(16))) CoopSmem u;
  cg::grid_group grid = cg::this_grid();

  for (int st = 0; st < NQ; ++st) {
    const int wr = (st < NQ - 1) ? 1 : 0;
    const float* rin = (st == 0) ? x : resid;
    screen_stage(u.s, rin, resid,
                 Ef16 + (size_t)st * KCODES * DDIM,
                 embed + (size_t)st * KCODES * DDIM,
                 enorm + (size_t)st * KCODES,
                 codes + (size_t)st * M_TOTAL,
                 flist + (size_t)st * M_TOTAL, nfp + st, wr);
    grid.sync();                  // flags + screen resid visible device-wide
    if (blockIdx.x < FIXGRID)
      fixup_stage(u.f, x, embed, enorm, codes, resid,
                  flist + (size_t)st * M_TOTAL, nfp + st, st, wr);
    grid.sync();                  // corrected codes/resid visible before next stage
  }
}

// ---------------- fallback wrappers (exact round-0 multi-kernel path) ----------------
__global__ __launch_bounds__(256, 4) void rvq_screen_k(
    const float* rin, float* rout, const _Float16* __restrict__ EfS,
    const float* __restrict__ embS, const float* __restrict__ enS,
    int* __restrict__ codesS, int* __restrict__ flistS, int* __restrict__ nfpS,
    int write_resid)
{
  __shared__ __attribute__((aligned(16))) ScreenSmem S;
  screen_stage(S, rin, rout, EfS, embS, enS, codesS, flistS, nfpS, write_resid);
}

__global__ __launch_bounds__(256) void rvq_fixup_k(
    const float* __restrict__ x,
    const float* __restrict__ embed_all, const float* __restrict__ enorm_all,
    int* __restrict__ codes, float* __restrict__ resid,
    const int* __restrict__ flistS, const int* __restrict__ nfpS,
    int stage, int write_resid)
{
  __shared__ __attribute__((aligned(16))) FixSmem F;
  fixup_stage(F, x, embed_all, enorm_all, codes, resid, flistS, nfpS, stage, write_resid);
}

extern "C" void kernel_launch(void* const* d_in, const int* in_sizes, int n_in,
                              void* d_out, int out_size, void* d_ws, size_t ws_size,
                              hipStream_t stream) {
  (void)in_sizes; (void)n_in; (void)out_size;
  const float* x = (const float*)d_in[0];
  const float* embed = (const float*)d_in[1];
  int* codes = (int*)d_out;

  const size_t R_BYTES   = (size_t)M_TOTAL * DDIM * 4;            // 32 MB f32 residual
  const size_t E16_BYTES = (size_t)NQ * KCODES * DDIM * 2;        // 2 MB f16 codebook
  const size_t EN_BYTES  = (size_t)NQ * KCODES * 4;               // 32 KB
  const size_t FL_BYTES  = (size_t)NQ * M_TOTAL * 4;              // 2 MB flag lists
  const size_t need = R_BYTES + E16_BYTES + EN_BYTES + FL_BYTES + 256;

  if (ws_size >= need) {
    char* w = (char*)d_ws;
    float* resid   = (float*)w;        w += R_BYTES;
    _Float16* Ef16 = (_Float16*)w;     w += E16_BYTES;
    float* enorm   = (float*)w;        w += EN_BYTES;
    int* flist     = (int*)w;          w += FL_BYTES;
    int* nfp       = (int*)w;

    enorm_kernel<<<dim3(NQ * KCODES / 4), dim3(256), 0, stream>>>(embed, enorm, nfp);
    esplit16_kernel<<<dim3(NQ * KCODES * DDIM / 8 / 256), dim3(256), 0, stream>>>(embed, Ef16);

    const float* xa = x; float* ra = resid; const float* ea = embed;
    const _Float16* efa = Ef16; const float* ena = enorm;
    int* ca = codes; int* fla = flist; int* nfa = nfp;
    void* args[] = {&xa, &ra, &ea, &efa, &ena, &ca, &fla, &nfa};
    hipError_t err = hipLaunchCooperativeKernel(
        reinterpret_cast<void*>(rvq_coop), dim3(M_TOTAL / RROWS), dim3(256),
        args, 0, stream);

    if (err != hipSuccess) {
      (void)hipGetLastError();   // clear sticky error; run round-0 sequence
      for (int q = 0; q < NQ; ++q) {
        int wr = (q < NQ - 1) ? 1 : 0;
        const float* rin = (q == 0) ? x : resid;
        rvq_screen_k<<<dim3(M_TOTAL / RROWS), dim3(256), 0, stream>>>(
            rin, resid,
            Ef16 + (size_t)q * KCODES * DDIM,
            embed + (size_t)q * KCODES * DDIM,
            enorm + (size_t)q * KCODES,
            codes + (size_t)q * M_TOTAL,
            flist + (size_t)q * M_TOTAL, nfp + q, wr);
        rvq_fixup_k<<<dim3(FIXGRID), dim3(256), 0, stream>>>(
            x, embed, enorm, codes, resid,
            flist + (size_t)q * M_TOTAL, nfp + q, q, wr);
      }
    }
  } else {
    // minimal-workspace fallback: screen-only path is not valid without flist;
    // use the screen kernel with fixup disabled is NOT exact, so run the
    // multi-kernel exact path packed into whatever ws exists (requires resid+enorm).
    const size_t resid_elems = (size_t)M_TOTAL * DDIM;
    float* resid = (float*)d_ws;
    float* enorm = (float*)d_ws + resid_elems;
    int*   nfp   = (int*)(enorm + (size_t)NQ * KCODES);
    int*   flist = nfp + NQ;   // reuse: needs NQ*M_TOTAL ints — only if ws allows
    _Float16* Ef16 = (_Float16*)(flist + (size_t)NQ * M_TOTAL);

    enorm_kernel<<<dim3(NQ * KCODES / 4), dim3(256), 0, stream>>>(embed, enorm, nfp);
    esplit16_kernel<<<dim3(NQ * KCODES * DDIM / 8 / 256), dim3(256), 0, stream>>>(embed, Ef16);
    for (int q = 0; q < NQ; ++q) {
      int wr = (q < NQ - 1) ? 1 : 0;
      const float* rin = (q == 0) ? x : resid;
      rvq_screen_k<<<dim3(M_TOTAL / RROWS), dim3(256), 0, stream>>>(
          rin, resid,
          Ef16 + (size_t)q * KCODES * DDIM,
          embed + (size_t)q * KCODES * DDIM,
          enorm + (size_t)q * KCODES,
          codes + (size_t)q * M_TOTAL,
          flist + (size_t)q * M_TOTAL, nfp + q, wr);
      rvq_fixup_k<<<dim3(FIXGRID), dim3(256), 0, stream>>>(
          x, embed, enorm, codes, resid,
          flist + (size_t)q * M_TOTAL, nfp + q, q, wr);
    }
  }
}